// Round 7
// baseline (2519.021 us; speedup 1.0000x reference)
//
#include <hip/hip_runtime.h>

typedef __attribute__((ext_vector_type(8))) short short8;
typedef __attribute__((ext_vector_type(4))) short short4v;
typedef __attribute__((ext_vector_type(4))) float f32x4;

__device__ inline short f2bf(float f) {
    union { float f; unsigned u; } v; v.f = f;
    unsigned r = v.u + 0x7fffu + ((v.u >> 16) & 1u);
    return (short)(r >> 16);
}

__device__ __forceinline__ void gload16(const short* g, short* l) {
    __builtin_amdgcn_global_load_lds(
        (const __attribute__((address_space(1))) unsigned int*)g,
        (__attribute__((address_space(3))) unsigned int*)l, 16, 0, 0);
}

// ---------------- elementwise f32 -> bf16 ----------------
__global__ __launch_bounds__(256) void cvt_f32_to_bf16(const float* __restrict__ in,
                                                       short* __restrict__ out, int n4) {
    int i = blockIdx.x * 256 + threadIdx.x;
    if (i >= n4) return;
    float4 v = ((const float4*)in)[i];
    short4v o;
    o[0] = f2bf(v.x); o[1] = f2bf(v.y); o[2] = f2bf(v.z); o[3] = f2bf(v.w);
    ((short4v*)out)[i] = o;
}

// ---------------- tiled transpose (R x C) f32 -> bf16 (C x R) ----------------
__global__ __launch_bounds__(256) void transpose_to_bf16(const float* __restrict__ in,
                                                         short* __restrict__ out,
                                                         int R, int C) {
    __shared__ short tile[64][66];
    int r0 = blockIdx.x * 64, c0 = blockIdx.y * 64;
    int tid = threadIdx.x;
#pragma unroll
    for (int i = 0; i < 16; i++) {
        int idx = i * 256 + tid;
        int r = idx >> 6, c = idx & 63;
        tile[r][c] = f2bf(in[(size_t)(r0 + r) * C + (c0 + c)]);
    }
    __syncthreads();
#pragma unroll
    for (int i = 0; i < 16; i++) {
        int idx = i * 256 + tid;
        int c = idx >> 6, r = idx & 63;
        out[(size_t)(c0 + c) * R + (r0 + r)] = tile[r][c];
    }
}

// ---------------- bf16 GEMM BMx256, BK=32, 2-buf depth-1 counted-vmcnt ----------------
// C(MxN) = A(MxK) * Bt(NxK)^T. 512 thr = 8 waves (2M x 4N); per-wave (BM/2)x64 out.
// 64KB (BM=256) / 48KB (BM=128) LDS -> 2 blocks/CU; independent blocks overlap barriers.
// LDS rows 64B, chunk stored at cpos = g ^ ((row>>1)&3); reads at ce = t4^((t15>>1)&3)
// are exact 2-way bank access (free, verified 0 conflicts in r6).
template <int EPI, int BM>
__global__ __launch_bounds__(512, 4) void gemm_bt(const short* __restrict__ A,
                                                  const short* __restrict__ Bt,
                                                  int M, int N, int K,
                                                  short* __restrict__ O0, short* __restrict__ O1,
                                                  short* __restrict__ O2, float* __restrict__ OF,
                                                  float qscale) {
    constexpr int MREP = BM / 32;        // 16-row fragments per wave (8 or 4)
    constexpr int APW = BM / 128;        // A-stage loads per wave (2 or 1)
    __shared__ short Als[2][BM * 32];
    __shared__ short Bls[2][256 * 32];
    int tid = threadIdx.x;
    int lane = tid & 63, wid = tid >> 6;
    int wr = wid >> 2, wc = wid & 3;
    int ntn = N >> 8;
    int nwg = gridDim.x;
    // T1: bijective XCD swizzle (nwg % 8 == 0)
    int cpx = nwg >> 3;
    int bid = blockIdx.x;
    int wgid = (bid & 7) * cpx + (bid >> 3);
    int mt = wgid / ntn, nt = wgid % ntn;
    int row0 = mt * BM, col0 = nt << 8;
    int t15 = lane & 15, t4 = lane >> 4;
    int ce = t4 ^ ((t15 >> 1) & 3);            // read-side swizzled chunk
    int srow = lane >> 2;                      // staging: row within 16-row seg
    int sg = (lane & 3) ^ ((lane >> 3) & 3);   // staging: inverse-swizzled global chunk

    f32x4 acc[MREP][4];
#pragma unroll
    for (int m = 0; m < MREP; m++)
#pragma unroll
        for (int n = 0; n < 4; n++) acc[m][n] = (f32x4){0.f, 0.f, 0.f, 0.f};

    int NT = K >> 5;   // >= 2

    auto stage = [&](int t, int b) {
        int k0 = t << 5;
#pragma unroll
        for (int i = 0; i < APW; i++) {
            int seg = wid * APW + i;
            int row = seg * 16 + srow;
            gload16(A + (size_t)(row0 + row) * K + k0 + sg * 8, &Als[b][seg * 512]);
        }
#pragma unroll
        for (int i = 0; i < 2; i++) {
            int seg = wid * 2 + i;
            int row = seg * 16 + srow;
            gload16(Bt + (size_t)(col0 + row) * K + k0 + sg * 8, &Bls[b][seg * 512]);
        }
    };

    stage(0, 0);

    for (int t = 0; t < NT; t++) {
        int b = t & 1;
        if (t + 1 < NT) {
            stage(t + 1, b ^ 1);
            if (APW == 2) asm volatile("s_waitcnt vmcnt(4)" ::: "memory");
            else          asm volatile("s_waitcnt vmcnt(3)" ::: "memory");
        } else {
            asm volatile("s_waitcnt vmcnt(0)" ::: "memory");
        }
        asm volatile("s_barrier" ::: "memory");   // tile t fully staged

        short8 af[MREP], bfr[4];
#pragma unroll
        for (int m = 0; m < MREP; m++)
            af[m] = *(short8*)(&Als[b][(wr * (BM / 2) + m * 16 + t15) * 32 + ce * 8]);
#pragma unroll
        for (int n = 0; n < 4; n++)
            bfr[n] = *(short8*)(&Bls[b][(wc * 64 + n * 16 + t15) * 32 + ce * 8]);

        __builtin_amdgcn_s_setprio(1);
#pragma unroll
        for (int m = 0; m < MREP; m++)
#pragma unroll
            for (int n = 0; n < 4; n++)
                acc[m][n] = __builtin_amdgcn_mfma_f32_16x16x32_bf16(af[m], bfr[n], acc[m][n], 0, 0, 0);
        __builtin_amdgcn_s_setprio(0);

        asm volatile("s_barrier" ::: "memory");   // reads done -> buf b safe to restage at t+2
    }

#pragma unroll
    for (int m = 0; m < MREP; m++) {
#pragma unroll
        for (int n = 0; n < 4; n++) {
#pragma unroll
            for (int r = 0; r < 4; r++) {
                float v = acc[m][n][r];
                int gm = row0 + wr * (BM / 2) + m * 16 + t4 * 4 + r;
                int gn = col0 + wc * 64 + n * 16 + t15;
                if (EPI == 0) {
                    int part = gn >> 11, within = gn & 2047;
                    int h = within >> 7, dk = within & 127;
                    int bb = gm >> 11, s = gm & 2047;
                    int z = bb * 16 + h;
                    if (part == 0) O0[((size_t)z * 2048 + s) * 128 + dk] = f2bf(v * qscale);
                    else if (part == 1) O1[((size_t)z * 2048 + s) * 128 + dk] = f2bf(v);
                    else O2[((size_t)z * 128 + dk) * 2048 + s] = f2bf(v);  // V transposed
                } else {
                    OF[(size_t)gm * N + gn] = v;
                }
            }
        }
    }
}

// ---------------- causal flash attention (LDS-staged, paired-panel balanced) ----------------
__global__ __launch_bounds__(512, 4) void attn_fwd(const short* __restrict__ Q,
                                                   const short* __restrict__ Kb,
                                                   const short* __restrict__ Vt,
                                                   short* __restrict__ O) {
    __shared__ short Kls[2][64 * 128];
    __shared__ short Vls[128 * 64];
    __shared__ short Pls[8][16 * 72];
    int tid = threadIdx.x, lane = tid & 63, wid = tid >> 6;
    int bx = blockIdx.x, z = blockIdx.y;
    int pr = bx >> 1, hh = bx & 1;
    int qpan = (wid < 4) ? pr : (15 - pr);
    int t15 = lane & 15, t4 = lane >> 4;
    const short* Qh = Q + (size_t)z * 2048 * 128;
    const short* Kh = Kb + (size_t)z * 2048 * 128;
    const short* Vh = Vt + (size_t)z * 128 * 2048;
    int q0w = qpan * 128 + hh * 64 + (wid & 3) * 16;

    short8 qf[4];
    {
        const short* qrow = Qh + (size_t)(q0w + t15) * 128;
#pragma unroll
        for (int s = 0; s < 4; s++) qf[s] = *(const short8*)(qrow + s * 32 + t4 * 8);
    }

    f32x4 o[8];
#pragma unroll
    for (int st = 0; st < 8; st++) o[st] = (f32x4){0.f, 0.f, 0.f, 0.f};
    float m_r[4], l_r[4];
#pragma unroll
    for (int r = 0; r < 4; r++) { m_r[r] = -1e30f; l_r[r] = 0.f; }

    auto stageK = [&](int t, int buf) {
#pragma unroll
        for (int i = 0; i < 2; i++) {
            int seg = wid * 2 + i;
            int row = seg * 4 + t4;
            int kl = (lane & 15) ^ (row & 7);
            gload16(Kh + (size_t)(t * 64 + row) * 128 + kl * 8, &Kls[buf][seg * 512]);
        }
    };
    auto stageV = [&](int t) {
#pragma unroll
        for (int i = 0; i < 2; i++) {
            int seg = wid * 2 + i;
            int row = seg * 8 + (lane >> 3);
            int kl = (lane & 7) ^ (row & 7);
            gload16(Vh + (size_t)row * 2048 + t * 64 + kl * 8, &Vls[seg * 512]);
        }
    };

    int nt = 2 * (15 - pr) + 2;
    stageK(0, 0);
    __syncthreads();

    for (int t = 0; t < nt; t++) {
        int buf = t & 1;
        stageV(t);
        bool active = (t * 64 <= q0w + 15);

        if (active) {
            f32x4 sc[4];
#pragma unroll
            for (int c = 0; c < 4; c++) {
                sc[c] = (f32x4){0.f, 0.f, 0.f, 0.f};
#pragma unroll
                for (int s = 0; s < 4; s++) {
                    int row = c * 16 + t15;
                    int ck = (s * 4 + t4) ^ (row & 7);
                    short8 kf = *(short8*)(&Kls[buf][row * 128 + ck * 8]);
                    sc[c] = __builtin_amdgcn_mfma_f32_16x16x32_bf16(qf[s], kf, sc[c], 0, 0, 0);
                }
            }

            if (t * 64 + 63 > q0w) {
#pragma unroll
                for (int c = 0; c < 4; c++)
#pragma unroll
                    for (int r = 0; r < 4; r++) {
                        int kv = t * 64 + c * 16 + t15, qq = q0w + t4 * 4 + r;
                        if (kv > qq) sc[c][r] = -1e30f;
                    }
            }

            float tm[4];
#pragma unroll
            for (int r = 0; r < 4; r++)
                tm[r] = fmaxf(fmaxf(sc[0][r], sc[1][r]), fmaxf(sc[2][r], sc[3][r]));
            bool need = (tm[0] > m_r[0] + 8.f) | (tm[1] > m_r[1] + 8.f) |
                        (tm[2] > m_r[2] + 8.f) | (tm[3] > m_r[3] + 8.f);
            if (__any(need)) {
#pragma unroll
                for (int r = 0; r < 4; r++) {
#pragma unroll
                    for (int msk = 1; msk <= 8; msk <<= 1)
                        tm[r] = fmaxf(tm[r], __shfl_xor(tm[r], msk));
                    float mn = fmaxf(m_r[r], tm[r]);
                    float scf = __expf(m_r[r] - mn);
                    m_r[r] = mn;
                    l_r[r] *= scf;
#pragma unroll
                    for (int st = 0; st < 8; st++) o[st][r] *= scf;
                }
            }
#pragma unroll
            for (int r = 0; r < 4; r++) {
#pragma unroll
                for (int c = 0; c < 4; c++) {
                    float pv = __expf(sc[c][r] - m_r[r]);
                    Pls[wid][(t4 * 4 + r) * 72 + c * 16 + t15] = f2bf(pv);
                    l_r[r] += pv;
                }
            }
        }

        __syncthreads();
        if (t + 1 < nt) stageK(t + 1, buf ^ 1);

        if (active) {
            short8 pa[2];
#pragma unroll
            for (int s2 = 0; s2 < 2; s2++)
                pa[s2] = *(short8*)(&Pls[wid][0] + t15 * 72 + s2 * 32 + t4 * 8);
#pragma unroll
            for (int st = 0; st < 8; st++) {
#pragma unroll
                for (int s2 = 0; s2 < 2; s2++) {
                    int row = st * 16 + t15;
                    int ck = (s2 * 4 + t4) ^ (row & 7);
                    short8 vf = *(short8*)(&Vls[row * 64 + ck * 8]);
                    o[st] = __builtin_amdgcn_mfma_f32_16x16x32_bf16(pa[s2], vf, o[st], 0, 0, 0);
                }
            }
        }

        __syncthreads();
    }

#pragma unroll
    for (int r = 0; r < 4; r++)
#pragma unroll
        for (int msk = 1; msk <= 8; msk <<= 1)
            l_r[r] += __shfl_xor(l_r[r], msk);

    int b = z >> 4, h = z & 15;
#pragma unroll
    for (int st = 0; st < 8; st++)
#pragma unroll
        for (int r = 0; r < 4; r++) {
            int s = q0w + t4 * 4 + r;
            float val = o[st][r] / l_r[r];
            O[((size_t)b * 2048 + s) * 2048 + h * 128 + st * 16 + t15] = f2bf(val);
        }
}

extern "C" void kernel_launch(void* const* d_in, const int* in_sizes, int n_in,
                              void* d_out, int out_size, void* d_ws, size_t ws_size,
                              hipStream_t stream) {
    const float* x = (const float*)d_in[0];      // (4,2048,2048)
    const float* Wqkv = (const float*)d_in[1];   // (2048,6144)
    const float* Wo = (const float*)d_in[2];     // (2048,2048)

    const int B = 4, S = 2048, D = 2048, DK = 128;
    const int M = B * S;          // 8192
    const int N1 = 3 * D;         // 6144
    (void)in_sizes; (void)n_in; (void)out_size; (void)ws_size;

    char* ws = (char*)d_ws;
    size_t off = 0;
    short* x_bf = (short*)(ws + off);   off += (size_t)M * D * 2;
    short* wqkv_t = (short*)(ws + off); off += (size_t)N1 * D * 2;
    short* wo_t = (short*)(ws + off);   off += (size_t)D * D * 2;
    short* Qb = (short*)(ws + off);     off += (size_t)64 * S * DK * 2;
    short* Kb = (short*)(ws + off);     off += (size_t)64 * S * DK * 2;
    short* Vt = (short*)(ws + off);     off += (size_t)64 * S * DK * 2;
    short* Ob = (short*)(ws + off);     off += (size_t)M * D * 2;

    // 1. x -> bf16
    cvt_f32_to_bf16<<<(M * D / 4 + 255) / 256, 256, 0, stream>>>(x, x_bf, M * D / 4);
    // 2. Wqkv^T -> bf16 (N1 x D)
    transpose_to_bf16<<<dim3(D / 64, N1 / 64, 1), 256, 0, stream>>>(Wqkv, wqkv_t, D, N1);
    // 3. Wo^T -> bf16 (D x D)
    transpose_to_bf16<<<dim3(D / 64, D / 64, 1), 256, 0, stream>>>(Wo, wo_t, D, D);
    // 4. GEMM1: qkv = x @ Wqkv -> Q(scaled)/K/V^T   (256x256 tile, 768 blocks, 2/CU)
    gemm_bt<0, 256><<<(M / 256) * (N1 / 256), 512, 0, stream>>>(
        x_bf, wqkv_t, M, N1, D, Qb, Kb, Vt, nullptr, 0.08838834764831845f);
    // 5. attention (paired-panel balanced)
    attn_fwd<<<dim3(16, 64), 512, 0, stream>>>(Qb, Kb, Vt, Ob);
    // 6. GEMM2: out = O @ Wo (f32)                  (128x256 tile, 512 blocks, 2/CU)
    gemm_bt<1, 128><<<(M / 128) * (D / 256), 512, 0, stream>>>(
        Ob, wo_t, M, D, D, nullptr, nullptr, nullptr, (float*)d_out, 1.0f);
}

// Round 8
// 518.813 us; speedup vs baseline: 4.8554x; 4.8554x over previous
//
#include <hip/hip_runtime.h>

typedef __attribute__((ext_vector_type(8))) short short8;
typedef __attribute__((ext_vector_type(4))) short short4v;
typedef __attribute__((ext_vector_type(4))) float f32x4;

__device__ inline short f2bf(float f) {
    union { float f; unsigned u; } v; v.f = f;
    unsigned r = v.u + 0x7fffu + ((v.u >> 16) & 1u);
    return (short)(r >> 16);
}

__device__ __forceinline__ void gload16(const short* g, short* l) {
    __builtin_amdgcn_global_load_lds(
        (const __attribute__((address_space(1))) unsigned int*)g,
        (__attribute__((address_space(3))) unsigned int*)l, 16, 0, 0);
}

// ---------------- elementwise f32 -> bf16 ----------------
__global__ __launch_bounds__(256) void cvt_f32_to_bf16(const float* __restrict__ in,
                                                       short* __restrict__ out, int n4) {
    int i = blockIdx.x * 256 + threadIdx.x;
    if (i >= n4) return;
    float4 v = ((const float4*)in)[i];
    short4v o;
    o[0] = f2bf(v.x); o[1] = f2bf(v.y); o[2] = f2bf(v.z); o[3] = f2bf(v.w);
    ((short4v*)out)[i] = o;
}

// ---------------- tiled transpose (R x C) f32 -> bf16 (C x R) ----------------
__global__ __launch_bounds__(256) void transpose_to_bf16(const float* __restrict__ in,
                                                         short* __restrict__ out,
                                                         int R, int C) {
    __shared__ short tile[64][66];
    int r0 = blockIdx.x * 64, c0 = blockIdx.y * 64;
    int tid = threadIdx.x;
#pragma unroll
    for (int i = 0; i < 16; i++) {
        int idx = i * 256 + tid;
        int r = idx >> 6, c = idx & 63;
        tile[r][c] = f2bf(in[(size_t)(r0 + r) * C + (c0 + c)]);
    }
    __syncthreads();
#pragma unroll
    for (int i = 0; i < 16; i++) {
        int idx = i * 256 + tid;
        int c = idx >> 6, r = idx & 63;
        out[(size_t)(c0 + c) * R + (r0 + r)] = tile[r][c];
    }
}

// ---------------- bf16 GEMM 128x128, BK=64, 2-buf 1-barrier (T3-minimum) ----------------
// C(MxN) = A(MxK) * Bt(NxK)^T. 256 thr = 4 waves (2x2); per-wave 64x64 out.
// LDS 64KB -> 2 blocks/CU. Per tile: stage(t+1,buf^1) -> ds_read+MFMA(buf) ->
// one __syncthreads (drains vmcnt: staged tile visible; WAR: buf re-staged only
// at t+2, after this barrier). Staging latency hides under compute.
// LDS rows 128B, chunk stored at slot g^(row&7); reads at ck=(ks*4+t4)^(row&7):
// measured 0 bank conflicts (r4/r6).
template <int EPI>
__global__ __launch_bounds__(256) void gemm_bt(const short* __restrict__ A,
                                               const short* __restrict__ Bt,
                                               int M, int N, int K,
                                               short* __restrict__ O0, short* __restrict__ O1,
                                               short* __restrict__ O2, float* __restrict__ OF,
                                               float qscale) {
    __shared__ short Als[2][128 * 64];
    __shared__ short Bls[2][128 * 64];
    int tid = threadIdx.x;
    int lane = tid & 63, wid = tid >> 6;
    int wr = wid >> 1, wc = wid & 1;
    int ntn = N >> 7;
    int nwg = gridDim.x;
    // T1: bijective XCD swizzle (nwg % 8 == 0)
    int cpx = nwg >> 3;
    int bid = blockIdx.x;
    int wgid = (bid & 7) * cpx + (bid >> 3);
    int mt = wgid / ntn, nt = wgid % ntn;
    int row0 = mt << 7, col0 = nt << 7;
    int t15 = lane & 15, t4 = lane >> 4;
    int lrow = lane >> 3;
    int schunk = (lane & 7) ^ lrow;   // pre-inverse-swizzled global 16B chunk

    f32x4 acc[4][4];
#pragma unroll
    for (int m = 0; m < 4; m++)
#pragma unroll
        for (int n = 0; n < 4; n++) acc[m][n] = (f32x4){0.f, 0.f, 0.f, 0.f};

    int NT = K >> 6;   // >= 2

    auto stage = [&](int t, int b) {
        int k0 = t << 6;
#pragma unroll
        for (int i = 0; i < 4; i++) {
            int seg = wid * 4 + i;        // 16 segs x 8 rows
            int row = seg * 8 + lrow;
            gload16(A + (size_t)(row0 + row) * K + k0 + schunk * 8, &Als[b][seg * 512]);
            gload16(Bt + (size_t)(col0 + row) * K + k0 + schunk * 8, &Bls[b][seg * 512]);
        }
    };

    stage(0, 0);
    __syncthreads();                       // tile 0 staged & visible

    for (int t = 0; t < NT; t++) {
        int b = t & 1;
        if (t + 1 < NT) stage(t + 1, b ^ 1);   // overlaps with compute below

#pragma unroll
        for (int ks = 0; ks < 2; ks++) {
            short8 af[4], bfr[4];
#pragma unroll
            for (int m = 0; m < 4; m++) {
                int row = wr * 64 + m * 16 + t15;
                int ck = (ks * 4 + t4) ^ (row & 7);
                af[m] = *(short8*)(&Als[b][row * 64 + ck * 8]);
            }
#pragma unroll
            for (int n = 0; n < 4; n++) {
                int row = wc * 64 + n * 16 + t15;
                int ck = (ks * 4 + t4) ^ (row & 7);
                bfr[n] = *(short8*)(&Bls[b][row * 64 + ck * 8]);
            }
#pragma unroll
            for (int m = 0; m < 4; m++)
#pragma unroll
                for (int n = 0; n < 4; n++)
                    acc[m][n] = __builtin_amdgcn_mfma_f32_16x16x32_bf16(af[m], bfr[n], acc[m][n], 0, 0, 0);
        }

        __syncthreads();   // drains vmcnt (tile t+1 visible) + WAR for buf b
    }

#pragma unroll
    for (int m = 0; m < 4; m++) {
#pragma unroll
        for (int n = 0; n < 4; n++) {
#pragma unroll
            for (int r = 0; r < 4; r++) {
                float v = acc[m][n][r];
                int gm = row0 + wr * 64 + m * 16 + t4 * 4 + r;
                int gn = col0 + wc * 64 + n * 16 + t15;
                if (EPI == 0) {
                    int part = gn >> 11, within = gn & 2047;
                    int h = within >> 7, dk = within & 127;
                    int bb = gm >> 11, s = gm & 2047;
                    int z = bb * 16 + h;
                    if (part == 0) O0[((size_t)z * 2048 + s) * 128 + dk] = f2bf(v * qscale);
                    else if (part == 1) O1[((size_t)z * 2048 + s) * 128 + dk] = f2bf(v);
                    else O2[((size_t)z * 128 + dk) * 2048 + s] = f2bf(v);  // V transposed
                } else {
                    OF[(size_t)gm * N + gn] = v;
                }
            }
        }
    }
}

// ---------------- causal flash attention (LDS-staged, paired-panel balanced) ----------------
__global__ __launch_bounds__(512, 4) void attn_fwd(const short* __restrict__ Q,
                                                   const short* __restrict__ Kb,
                                                   const short* __restrict__ Vt,
                                                   short* __restrict__ O) {
    __shared__ short Kls[2][64 * 128];
    __shared__ short Vls[128 * 64];
    __shared__ short Pls[8][16 * 72];
    int tid = threadIdx.x, lane = tid & 63, wid = tid >> 6;
    int bx = blockIdx.x, z = blockIdx.y;
    int pr = bx >> 1, hh = bx & 1;
    int qpan = (wid < 4) ? pr : (15 - pr);
    int t15 = lane & 15, t4 = lane >> 4;
    const short* Qh = Q + (size_t)z * 2048 * 128;
    const short* Kh = Kb + (size_t)z * 2048 * 128;
    const short* Vh = Vt + (size_t)z * 128 * 2048;
    int q0w = qpan * 128 + hh * 64 + (wid & 3) * 16;

    short8 qf[4];
    {
        const short* qrow = Qh + (size_t)(q0w + t15) * 128;
#pragma unroll
        for (int s = 0; s < 4; s++) qf[s] = *(const short8*)(qrow + s * 32 + t4 * 8);
    }

    f32x4 o[8];
#pragma unroll
    for (int st = 0; st < 8; st++) o[st] = (f32x4){0.f, 0.f, 0.f, 0.f};
    float m_r[4], l_r[4];
#pragma unroll
    for (int r = 0; r < 4; r++) { m_r[r] = -1e30f; l_r[r] = 0.f; }

    auto stageK = [&](int t, int buf) {
#pragma unroll
        for (int i = 0; i < 2; i++) {
            int seg = wid * 2 + i;
            int row = seg * 4 + t4;
            int kl = (lane & 15) ^ (row & 7);
            gload16(Kh + (size_t)(t * 64 + row) * 128 + kl * 8, &Kls[buf][seg * 512]);
        }
    };
    auto stageV = [&](int t) {
#pragma unroll
        for (int i = 0; i < 2; i++) {
            int seg = wid * 2 + i;
            int row = seg * 8 + (lane >> 3);
            int kl = (lane & 7) ^ (row & 7);
            gload16(Vh + (size_t)row * 2048 + t * 64 + kl * 8, &Vls[seg * 512]);
        }
    };

    int nt = 2 * (15 - pr) + 2;
    stageK(0, 0);
    __syncthreads();

    for (int t = 0; t < nt; t++) {
        int buf = t & 1;
        stageV(t);
        bool active = (t * 64 <= q0w + 15);

        if (active) {
            f32x4 sc[4];
#pragma unroll
            for (int c = 0; c < 4; c++) {
                sc[c] = (f32x4){0.f, 0.f, 0.f, 0.f};
#pragma unroll
                for (int s = 0; s < 4; s++) {
                    int row = c * 16 + t15;
                    int ck = (s * 4 + t4) ^ (row & 7);
                    short8 kf = *(short8*)(&Kls[buf][row * 128 + ck * 8]);
                    sc[c] = __builtin_amdgcn_mfma_f32_16x16x32_bf16(qf[s], kf, sc[c], 0, 0, 0);
                }
            }

            if (t * 64 + 63 > q0w) {
#pragma unroll
                for (int c = 0; c < 4; c++)
#pragma unroll
                    for (int r = 0; r < 4; r++) {
                        int kv = t * 64 + c * 16 + t15, qq = q0w + t4 * 4 + r;
                        if (kv > qq) sc[c][r] = -1e30f;
                    }
            }

            float tm[4];
#pragma unroll
            for (int r = 0; r < 4; r++)
                tm[r] = fmaxf(fmaxf(sc[0][r], sc[1][r]), fmaxf(sc[2][r], sc[3][r]));
            bool need = (tm[0] > m_r[0] + 8.f) | (tm[1] > m_r[1] + 8.f) |
                        (tm[2] > m_r[2] + 8.f) | (tm[3] > m_r[3] + 8.f);
            if (__any(need)) {
#pragma unroll
                for (int r = 0; r < 4; r++) {
#pragma unroll
                    for (int msk = 1; msk <= 8; msk <<= 1)
                        tm[r] = fmaxf(tm[r], __shfl_xor(tm[r], msk));
                    float mn = fmaxf(m_r[r], tm[r]);
                    float scf = __expf(m_r[r] - mn);
                    m_r[r] = mn;
                    l_r[r] *= scf;
#pragma unroll
                    for (int st = 0; st < 8; st++) o[st][r] *= scf;
                }
            }
#pragma unroll
            for (int r = 0; r < 4; r++) {
#pragma unroll
                for (int c = 0; c < 4; c++) {
                    float pv = __expf(sc[c][r] - m_r[r]);
                    Pls[wid][(t4 * 4 + r) * 72 + c * 16 + t15] = f2bf(pv);
                    l_r[r] += pv;
                }
            }
        }

        __syncthreads();
        if (t + 1 < nt) stageK(t + 1, buf ^ 1);

        if (active) {
            short8 pa[2];
#pragma unroll
            for (int s2 = 0; s2 < 2; s2++)
                pa[s2] = *(short8*)(&Pls[wid][0] + t15 * 72 + s2 * 32 + t4 * 8);
#pragma unroll
            for (int st = 0; st < 8; st++) {
#pragma unroll
                for (int s2 = 0; s2 < 2; s2++) {
                    int row = st * 16 + t15;
                    int ck = (s2 * 4 + t4) ^ (row & 7);
                    short8 vf = *(short8*)(&Vls[row * 64 + ck * 8]);
                    o[st] = __builtin_amdgcn_mfma_f32_16x16x32_bf16(pa[s2], vf, o[st], 0, 0, 0);
                }
            }
        }

        __syncthreads();
    }

#pragma unroll
    for (int r = 0; r < 4; r++)
#pragma unroll
        for (int msk = 1; msk <= 8; msk <<= 1)
            l_r[r] += __shfl_xor(l_r[r], msk);

    int b = z >> 4, h = z & 15;
#pragma unroll
    for (int st = 0; st < 8; st++)
#pragma unroll
        for (int r = 0; r < 4; r++) {
            int s = q0w + t4 * 4 + r;
            float val = o[st][r] / l_r[r];
            O[((size_t)b * 2048 + s) * 2048 + h * 128 + st * 16 + t15] = f2bf(val);
        }
}

extern "C" void kernel_launch(void* const* d_in, const int* in_sizes, int n_in,
                              void* d_out, int out_size, void* d_ws, size_t ws_size,
                              hipStream_t stream) {
    const float* x = (const float*)d_in[0];      // (4,2048,2048)
    const float* Wqkv = (const float*)d_in[1];   // (2048,6144)
    const float* Wo = (const float*)d_in[2];     // (2048,2048)

    const int B = 4, S = 2048, D = 2048, DK = 128;
    const int M = B * S;          // 8192
    const int N1 = 3 * D;         // 6144
    (void)in_sizes; (void)n_in; (void)out_size; (void)ws_size;

    char* ws = (char*)d_ws;
    size_t off = 0;
    short* x_bf = (short*)(ws + off);   off += (size_t)M * D * 2;
    short* wqkv_t = (short*)(ws + off); off += (size_t)N1 * D * 2;
    short* wo_t = (short*)(ws + off);   off += (size_t)D * D * 2;
    short* Qb = (short*)(ws + off);     off += (size_t)64 * S * DK * 2;
    short* Kb = (short*)(ws + off);     off += (size_t)64 * S * DK * 2;
    short* Vt = (short*)(ws + off);     off += (size_t)64 * S * DK * 2;
    short* Ob = (short*)(ws + off);     off += (size_t)M * D * 2;

    // 1. x -> bf16
    cvt_f32_to_bf16<<<(M * D / 4 + 255) / 256, 256, 0, stream>>>(x, x_bf, M * D / 4);
    // 2. Wqkv^T -> bf16 (N1 x D)
    transpose_to_bf16<<<dim3(D / 64, N1 / 64, 1), 256, 0, stream>>>(Wqkv, wqkv_t, D, N1);
    // 3. Wo^T -> bf16 (D x D)
    transpose_to_bf16<<<dim3(D / 64, D / 64, 1), 256, 0, stream>>>(Wo, wo_t, D, D);
    // 4. GEMM1: qkv = x @ Wqkv -> Q(scaled)/K/V^T   (128x128, 3072 blocks)
    gemm_bt<0><<<(M / 128) * (N1 / 128), 256, 0, stream>>>(
        x_bf, wqkv_t, M, N1, D, Qb, Kb, Vt, nullptr, 0.08838834764831845f);
    // 5. attention (paired-panel balanced)
    attn_fwd<<<dim3(16, 64), 512, 0, stream>>>(Qb, Kb, Vt, Ob);
    // 6. GEMM2: out = O @ Wo (f32)                  (128x128, 1024 blocks)
    gemm_bt<1><<<(M / 128) * (D / 128), 256, 0, stream>>>(
        Ob, wo_t, M, D, D, nullptr, nullptr, nullptr, (float*)d_out, 1.0f);
}

// Round 9
// 483.188 us; speedup vs baseline: 5.2133x; 1.0737x over previous
//
#include <hip/hip_runtime.h>

typedef __attribute__((ext_vector_type(8))) short short8;
typedef __attribute__((ext_vector_type(4))) short short4v;
typedef __attribute__((ext_vector_type(4))) float f32x4;

__device__ inline short f2bf(float f) {
    union { float f; unsigned u; } v; v.f = f;
    unsigned r = v.u + 0x7fffu + ((v.u >> 16) & 1u);
    return (short)(r >> 16);
}

__device__ __forceinline__ void gload16(const short* g, short* l) {
    __builtin_amdgcn_global_load_lds(
        (const __attribute__((address_space(1))) unsigned int*)g,
        (__attribute__((address_space(3))) unsigned int*)l, 16, 0, 0);
}

// ---------------- elementwise f32 -> bf16 ----------------
__global__ __launch_bounds__(256) void cvt_f32_to_bf16(const float* __restrict__ in,
                                                       short* __restrict__ out, int n4) {
    int i = blockIdx.x * 256 + threadIdx.x;
    if (i >= n4) return;
    float4 v = ((const float4*)in)[i];
    short4v o;
    o[0] = f2bf(v.x); o[1] = f2bf(v.y); o[2] = f2bf(v.z); o[3] = f2bf(v.w);
    ((short4v*)out)[i] = o;
}

// ---------------- tiled transpose (R x C) f32 -> bf16 (C x R) ----------------
__global__ __launch_bounds__(256) void transpose_to_bf16(const float* __restrict__ in,
                                                         short* __restrict__ out,
                                                         int R, int C) {
    __shared__ short tile[64][66];
    int r0 = blockIdx.x * 64, c0 = blockIdx.y * 64;
    int tid = threadIdx.x;
#pragma unroll
    for (int i = 0; i < 16; i++) {
        int idx = i * 256 + tid;
        int r = idx >> 6, c = idx & 63;
        tile[r][c] = f2bf(in[(size_t)(r0 + r) * C + (c0 + c)]);
    }
    __syncthreads();
#pragma unroll
    for (int i = 0; i < 16; i++) {
        int idx = i * 256 + tid;
        int c = idx >> 6, r = idx & 63;
        out[(size_t)(c0 + c) * R + (r0 + r)] = tile[r][c];
    }
}

// ---------------- bf16 GEMM 128x128, BK=64, 2-buf 1-barrier (T3-minimum) ----------------
// C(MxN) = A(MxK) * Bt(NxK)^T. 256 thr = 4 waves (2x2); per-wave 64x64 out.
// LDS 64KB -> 2 blocks/CU. Per tile: stage(t+1,buf^1) -> ds_read+MFMA(buf) ->
// one __syncthreads. LDS rows 128B, chunk slot g^(row&7): 0 bank conflicts (r4/r6/r8).
// Block mapping: XCD x (= bid%8) owns 8-mt band [x*8, x*8+8), traversed
// COLUMN-major (nt outer, gm inner) so co-resident blocks form an 8x8 tile
// square: 8x concurrent reuse of both A- and B-panels; band A (4MB) ~L2-resident,
// B streamed once per band (r8's row-major band re-streamed B 8x -> 774MB FETCH).
// Requires gridDim.x == 8 * 8 * (N/128) and M/128 == 64 (both launches satisfy).
template <int EPI>
__global__ __launch_bounds__(256) void gemm_bt(const short* __restrict__ A,
                                               const short* __restrict__ Bt,
                                               int M, int N, int K,
                                               short* __restrict__ O0, short* __restrict__ O1,
                                               short* __restrict__ O2, float* __restrict__ OF,
                                               float qscale) {
    __shared__ short Als[2][128 * 64];
    __shared__ short Bls[2][128 * 64];
    int tid = threadIdx.x;
    int lane = tid & 63, wid = tid >> 6;
    int wr = wid >> 1, wc = wid & 1;
    int bid = blockIdx.x;
    int xcd = bid & 7;
    int k = bid >> 3;
    int nt = k >> 3;           // column within band (0..ntn-1)
    int gm = k & 7;            // row within band
    int mt = (xcd << 3) + gm;  // band x*8 .. x*8+7
    int row0 = mt << 7, col0 = nt << 7;
    int t15 = lane & 15, t4 = lane >> 4;
    int lrow = lane >> 3;
    int schunk = (lane & 7) ^ lrow;   // pre-inverse-swizzled global 16B chunk

    f32x4 acc[4][4];
#pragma unroll
    for (int m = 0; m < 4; m++)
#pragma unroll
        for (int n = 0; n < 4; n++) acc[m][n] = (f32x4){0.f, 0.f, 0.f, 0.f};

    int NT = K >> 6;   // >= 2

    auto stage = [&](int t, int b) {
        int k0 = t << 6;
#pragma unroll
        for (int i = 0; i < 4; i++) {
            int seg = wid * 4 + i;        // 16 segs x 8 rows
            int row = seg * 8 + lrow;
            gload16(A + (size_t)(row0 + row) * K + k0 + schunk * 8, &Als[b][seg * 512]);
            gload16(Bt + (size_t)(col0 + row) * K + k0 + schunk * 8, &Bls[b][seg * 512]);
        }
    };

    stage(0, 0);
    __syncthreads();                       // tile 0 staged & visible

    for (int t = 0; t < NT; t++) {
        int b = t & 1;
        if (t + 1 < NT) stage(t + 1, b ^ 1);   // overlaps with compute below

#pragma unroll
        for (int ks = 0; ks < 2; ks++) {
            short8 af[4], bfr[4];
#pragma unroll
            for (int m = 0; m < 4; m++) {
                int row = wr * 64 + m * 16 + t15;
                int ck = (ks * 4 + t4) ^ (row & 7);
                af[m] = *(short8*)(&Als[b][row * 64 + ck * 8]);
            }
#pragma unroll
            for (int n = 0; n < 4; n++) {
                int row = wc * 64 + n * 16 + t15;
                int ck = (ks * 4 + t4) ^ (row & 7);
                bfr[n] = *(short8*)(&Bls[b][row * 64 + ck * 8]);
            }
#pragma unroll
            for (int m = 0; m < 4; m++)
#pragma unroll
                for (int n = 0; n < 4; n++)
                    acc[m][n] = __builtin_amdgcn_mfma_f32_16x16x32_bf16(af[m], bfr[n], acc[m][n], 0, 0, 0);
        }

        __syncthreads();   // drains vmcnt (tile t+1 visible) + WAR for buf b
    }

#pragma unroll
    for (int m = 0; m < 4; m++) {
#pragma unroll
        for (int n = 0; n < 4; n++) {
#pragma unroll
            for (int r = 0; r < 4; r++) {
                float v = acc[m][n][r];
                int gm2 = row0 + wr * 64 + m * 16 + t4 * 4 + r;
                int gn = col0 + wc * 64 + n * 16 + t15;
                if (EPI == 0) {
                    int part = gn >> 11, within = gn & 2047;
                    int h = within >> 7, dk = within & 127;
                    int bb = gm2 >> 11, s = gm2 & 2047;
                    int z = bb * 16 + h;
                    if (part == 0) O0[((size_t)z * 2048 + s) * 128 + dk] = f2bf(v * qscale);
                    else if (part == 1) O1[((size_t)z * 2048 + s) * 128 + dk] = f2bf(v);
                    else O2[((size_t)z * 128 + dk) * 2048 + s] = f2bf(v);  // V transposed
                } else {
                    OF[(size_t)gm2 * N + gn] = v;
                }
            }
        }
    }
}

// ---------------- causal flash attention (LDS-staged, paired-panel balanced) ----------------
__global__ __launch_bounds__(512, 4) void attn_fwd(const short* __restrict__ Q,
                                                   const short* __restrict__ Kb,
                                                   const short* __restrict__ Vt,
                                                   short* __restrict__ O) {
    __shared__ short Kls[2][64 * 128];
    __shared__ short Vls[128 * 64];
    __shared__ short Pls[8][16 * 72];
    int tid = threadIdx.x, lane = tid & 63, wid = tid >> 6;
    int bx = blockIdx.x, z = blockIdx.y;
    int pr = bx >> 1, hh = bx & 1;
    int qpan = (wid < 4) ? pr : (15 - pr);
    int t15 = lane & 15, t4 = lane >> 4;
    const short* Qh = Q + (size_t)z * 2048 * 128;
    const short* Kh = Kb + (size_t)z * 2048 * 128;
    const short* Vh = Vt + (size_t)z * 128 * 2048;
    int q0w = qpan * 128 + hh * 64 + (wid & 3) * 16;

    short8 qf[4];
    {
        const short* qrow = Qh + (size_t)(q0w + t15) * 128;
#pragma unroll
        for (int s = 0; s < 4; s++) qf[s] = *(const short8*)(qrow + s * 32 + t4 * 8);
    }

    f32x4 o[8];
#pragma unroll
    for (int st = 0; st < 8; st++) o[st] = (f32x4){0.f, 0.f, 0.f, 0.f};
    float m_r[4], l_r[4];
#pragma unroll
    for (int r = 0; r < 4; r++) { m_r[r] = -1e30f; l_r[r] = 0.f; }

    auto stageK = [&](int t, int buf) {
#pragma unroll
        for (int i = 0; i < 2; i++) {
            int seg = wid * 2 + i;
            int row = seg * 4 + t4;
            int kl = (lane & 15) ^ (row & 7);
            gload16(Kh + (size_t)(t * 64 + row) * 128 + kl * 8, &Kls[buf][seg * 512]);
        }
    };
    auto stageV = [&](int t) {
#pragma unroll
        for (int i = 0; i < 2; i++) {
            int seg = wid * 2 + i;
            int row = seg * 8 + (lane >> 3);
            int kl = (lane & 7) ^ (row & 7);
            gload16(Vh + (size_t)row * 2048 + t * 64 + kl * 8, &Vls[seg * 512]);
        }
    };

    int nt = 2 * (15 - pr) + 2;
    stageK(0, 0);
    __syncthreads();

    for (int t = 0; t < nt; t++) {
        int buf = t & 1;
        stageV(t);
        bool active = (t * 64 <= q0w + 15);

        if (active) {
            f32x4 sc[4];
#pragma unroll
            for (int c = 0; c < 4; c++) {
                sc[c] = (f32x4){0.f, 0.f, 0.f, 0.f};
#pragma unroll
                for (int s = 0; s < 4; s++) {
                    int row = c * 16 + t15;
                    int ck = (s * 4 + t4) ^ (row & 7);
                    short8 kf = *(short8*)(&Kls[buf][row * 128 + ck * 8]);
                    sc[c] = __builtin_amdgcn_mfma_f32_16x16x32_bf16(qf[s], kf, sc[c], 0, 0, 0);
                }
            }

            if (t * 64 + 63 > q0w) {
#pragma unroll
                for (int c = 0; c < 4; c++)
#pragma unroll
                    for (int r = 0; r < 4; r++) {
                        int kv = t * 64 + c * 16 + t15, qq = q0w + t4 * 4 + r;
                        if (kv > qq) sc[c][r] = -1e30f;
                    }
            }

            float tm[4];
#pragma unroll
            for (int r = 0; r < 4; r++)
                tm[r] = fmaxf(fmaxf(sc[0][r], sc[1][r]), fmaxf(sc[2][r], sc[3][r]));
            bool need = (tm[0] > m_r[0] + 8.f) | (tm[1] > m_r[1] + 8.f) |
                        (tm[2] > m_r[2] + 8.f) | (tm[3] > m_r[3] + 8.f);
            if (__any(need)) {
#pragma unroll
                for (int r = 0; r < 4; r++) {
#pragma unroll
                    for (int msk = 1; msk <= 8; msk <<= 1)
                        tm[r] = fmaxf(tm[r], __shfl_xor(tm[r], msk));
                    float mn = fmaxf(m_r[r], tm[r]);
                    float scf = __expf(m_r[r] - mn);
                    m_r[r] = mn;
                    l_r[r] *= scf;
#pragma unroll
                    for (int st = 0; st < 8; st++) o[st][r] *= scf;
                }
            }
#pragma unroll
            for (int r = 0; r < 4; r++) {
#pragma unroll
                for (int c = 0; c < 4; c++) {
                    float pv = __expf(sc[c][r] - m_r[r]);
                    Pls[wid][(t4 * 4 + r) * 72 + c * 16 + t15] = f2bf(pv);
                    l_r[r] += pv;
                }
            }
        }

        __syncthreads();
        if (t + 1 < nt) stageK(t + 1, buf ^ 1);

        if (active) {
            short8 pa[2];
#pragma unroll
            for (int s2 = 0; s2 < 2; s2++)
                pa[s2] = *(short8*)(&Pls[wid][0] + t15 * 72 + s2 * 32 + t4 * 8);
#pragma unroll
            for (int st = 0; st < 8; st++) {
#pragma unroll
                for (int s2 = 0; s2 < 2; s2++) {
                    int row = st * 16 + t15;
                    int ck = (s2 * 4 + t4) ^ (row & 7);
                    short8 vf = *(short8*)(&Vls[row * 64 + ck * 8]);
                    o[st] = __builtin_amdgcn_mfma_f32_16x16x32_bf16(pa[s2], vf, o[st], 0, 0, 0);
                }
            }
        }

        __syncthreads();
    }

#pragma unroll
    for (int r = 0; r < 4; r++)
#pragma unroll
        for (int msk = 1; msk <= 8; msk <<= 1)
            l_r[r] += __shfl_xor(l_r[r], msk);

    int b = z >> 4, h = z & 15;
#pragma unroll
    for (int st = 0; st < 8; st++)
#pragma unroll
        for (int r = 0; r < 4; r++) {
            int s = q0w + t4 * 4 + r;
            float val = o[st][r] / l_r[r];
            O[((size_t)b * 2048 + s) * 2048 + h * 128 + st * 16 + t15] = f2bf(val);
        }
}

extern "C" void kernel_launch(void* const* d_in, const int* in_sizes, int n_in,
                              void* d_out, int out_size, void* d_ws, size_t ws_size,
                              hipStream_t stream) {
    const float* x = (const float*)d_in[0];      // (4,2048,2048)
    const float* Wqkv = (const float*)d_in[1];   // (2048,6144)
    const float* Wo = (const float*)d_in[2];     // (2048,2048)

    const int B = 4, S = 2048, D = 2048, DK = 128;
    const int M = B * S;          // 8192
    const int N1 = 3 * D;         // 6144
    (void)in_sizes; (void)n_in; (void)out_size; (void)ws_size;

    char* ws = (char*)d_ws;
    size_t off = 0;
    short* x_bf = (short*)(ws + off);   off += (size_t)M * D * 2;
    short* wqkv_t = (short*)(ws + off); off += (size_t)N1 * D * 2;
    short* wo_t = (short*)(ws + off);   off += (size_t)D * D * 2;
    short* Qb = (short*)(ws + off);     off += (size_t)64 * S * DK * 2;
    short* Kb = (short*)(ws + off);     off += (size_t)64 * S * DK * 2;
    short* Vt = (short*)(ws + off);     off += (size_t)64 * S * DK * 2;
    short* Ob = (short*)(ws + off);     off += (size_t)M * D * 2;

    // 1. x -> bf16
    cvt_f32_to_bf16<<<(M * D / 4 + 255) / 256, 256, 0, stream>>>(x, x_bf, M * D / 4);
    // 2. Wqkv^T -> bf16 (N1 x D)
    transpose_to_bf16<<<dim3(D / 64, N1 / 64, 1), 256, 0, stream>>>(Wqkv, wqkv_t, D, N1);
    // 3. Wo^T -> bf16 (D x D)
    transpose_to_bf16<<<dim3(D / 64, D / 64, 1), 256, 0, stream>>>(Wo, wo_t, D, D);
    // 4. GEMM1: qkv = x @ Wqkv -> Q(scaled)/K/V^T   (128x128, 3072 blocks, banded)
    gemm_bt<0><<<(M / 128) * (N1 / 128), 256, 0, stream>>>(
        x_bf, wqkv_t, M, N1, D, Qb, Kb, Vt, nullptr, 0.08838834764831845f);
    // 5. attention (paired-panel balanced)
    attn_fwd<<<dim3(16, 64), 512, 0, stream>>>(Qb, Kb, Vt, Ob);
    // 6. GEMM2: out = O @ Wo (f32)                  (128x128, 1024 blocks, banded)
    gemm_bt<1><<<(M / 128) * (D / 128), 256, 0, stream>>>(
        Ob, wo_t, M, D, D, nullptr, nullptr, nullptr, (float*)d_out, 1.0f);
}